// Round 3
// baseline (144.395 us; speedup 1.0000x reference)
//
#include <hip/hip_runtime.h>

static constexpr int B_ROWS  = 262144;
static constexpr int D       = 256;
static constexpr int NSAMP   = 5;
static constexpr int BLOCK   = 256;           // 4 waves
static constexpr int NBLOCKS = 2048;          // 8192 waves x 32 rows/wave = 262144
static constexpr int WPB     = BLOCK / 64;
static constexpr int ROWS_PER_WAVE = 32;

// log(max(sigmoid(x), eps))   = -min(log(1+e^{-x}), -ln eps)
// log(max(sigmoid(-x), 0.75)) = -min(log(1+e^{x}),  -ln 0.75)
static constexpr float NEG_LN_EPS  = 20.723265836946411f;   // -ln(1e-9)
static constexpr float NEG_LN_BETA = 0.28768207245178085f;  // -ln(0.75)

__device__ __forceinline__ float dot4(const float4 a, const float4 b) {
    return a.x * b.x + a.y * b.y + a.z * b.z + a.w * b.w;
}

__global__ __launch_bounds__(BLOCK) void sgns_main(
    const float* __restrict__ ctx, const float* __restrict__ tgt,
    const float* __restrict__ emb, const int* __restrict__ neg_idx,
    float* __restrict__ partials)
{
    __shared__ float smp[NSAMP][D];   // 5 KB; reads broadcast across 4-lane groups
    for (int i = threadIdx.x; i < NSAMP * D; i += BLOCK) {
        const int s = i >> 8, c = i & (D - 1);
        smp[s][c] = emb[(size_t)neg_idx[s] * D + c];
    }
    __syncthreads();

    const int lane = threadIdx.x & 63;
    const int wid  = threadIdx.x >> 6;
    const int sub  = lane & 3;        // position within 4-lane group
    const int grp  = lane >> 2;       // 0..15
    const int base = blockIdx.x * (WPB * ROWS_PER_WAVE) + wid * ROWS_PER_WAVE;

    // Row-set A = rows base..base+15, row-set B = rows base+16..base+31.
    const float* cpA = ctx + (size_t)(base + grp) * D + sub * 4;
    const float* tpA = tgt + (size_t)(base + grp) * D + sub * 4;
    const float* cpB = cpA + (size_t)16 * D;
    const float* tpB = tpA + (size_t)16 * D;

    float a0=0.f,a1=0.f,a2=0.f,a3=0.f,a4=0.f,a5=0.f;
    float b0=0.f,b1=0.f,b2=0.f,b3=0.f,b4=0.f,b5=0.f;

#pragma unroll 4
    for (int m = 0; m < 16; ++m) {
        const float4 cA = *reinterpret_cast<const float4*>(cpA + m * 16);
        const float4 tA = *reinterpret_cast<const float4*>(tpA + m * 16);
        const float4 cB = *reinterpret_cast<const float4*>(cpB + m * 16);
        const float4 tB = *reinterpret_cast<const float4*>(tpB + m * 16);
        const int sc = m * 16 + sub * 4;
        const float4 s0 = *reinterpret_cast<const float4*>(&smp[0][sc]);
        const float4 s1 = *reinterpret_cast<const float4*>(&smp[1][sc]);
        const float4 s2 = *reinterpret_cast<const float4*>(&smp[2][sc]);
        const float4 s3 = *reinterpret_cast<const float4*>(&smp[3][sc]);
        const float4 s4 = *reinterpret_cast<const float4*>(&smp[4][sc]);
        a0 += dot4(cA, tA); b0 += dot4(cB, tB);
        a1 += dot4(cA, s0); b1 += dot4(cB, s0);
        a2 += dot4(cA, s1); b2 += dot4(cB, s1);
        a3 += dot4(cA, s2); b3 += dot4(cB, s2);
        a4 += dot4(cA, s3); b4 += dot4(cB, s3);
        a5 += dot4(cA, s4); b5 += dot4(cB, s4);
    }

    // Reduce each dot across its 4-lane group (offsets 1,2 only).
    a0 += __shfl_xor(a0, 1, 64); a0 += __shfl_xor(a0, 2, 64);
    a1 += __shfl_xor(a1, 1, 64); a1 += __shfl_xor(a1, 2, 64);
    a2 += __shfl_xor(a2, 1, 64); a2 += __shfl_xor(a2, 2, 64);
    a3 += __shfl_xor(a3, 1, 64); a3 += __shfl_xor(a3, 2, 64);
    a4 += __shfl_xor(a4, 1, 64); a4 += __shfl_xor(a4, 2, 64);
    a5 += __shfl_xor(a5, 1, 64); a5 += __shfl_xor(a5, 2, 64);
    b0 += __shfl_xor(b0, 1, 64); b0 += __shfl_xor(b0, 2, 64);
    b1 += __shfl_xor(b1, 1, 64); b1 += __shfl_xor(b1, 2, 64);
    b2 += __shfl_xor(b2, 1, 64); b2 += __shfl_xor(b2, 2, 64);
    b3 += __shfl_xor(b3, 1, 64); b3 += __shfl_xor(b3, 2, 64);
    b4 += __shfl_xor(b4, 1, 64); b4 += __shfl_xor(b4, 2, 64);
    b5 += __shfl_xor(b5, 1, 64); b5 += __shfl_xor(b5, 2, 64);

    // 32 rows of loss per wave (each computed redundantly on 4 lanes).
    float acc;
    {
        float rA = -fminf(__logf(1.0f + __expf(-a0)), NEG_LN_EPS);
        rA -= fminf(__logf(1.0f + __expf(a1)), NEG_LN_BETA);
        rA -= fminf(__logf(1.0f + __expf(a2)), NEG_LN_BETA);
        rA -= fminf(__logf(1.0f + __expf(a3)), NEG_LN_BETA);
        rA -= fminf(__logf(1.0f + __expf(a4)), NEG_LN_BETA);
        rA -= fminf(__logf(1.0f + __expf(a5)), NEG_LN_BETA);
        float rB = -fminf(__logf(1.0f + __expf(-b0)), NEG_LN_EPS);
        rB -= fminf(__logf(1.0f + __expf(b1)), NEG_LN_BETA);
        rB -= fminf(__logf(1.0f + __expf(b2)), NEG_LN_BETA);
        rB -= fminf(__logf(1.0f + __expf(b3)), NEG_LN_BETA);
        rB -= fminf(__logf(1.0f + __expf(b4)), NEG_LN_BETA);
        rB -= fminf(__logf(1.0f + __expf(b5)), NEG_LN_BETA);
        acc = rA + rB;
    }

    // Full-wave reduce; each row counted 4x within its group.
#pragma unroll
    for (int off = 32; off > 0; off >>= 1) acc += __shfl_xor(acc, off, 64);
    acc *= 0.25f;

    __shared__ float blk[WPB];
    if (lane == 0) blk[wid] = acc;
    __syncthreads();
    if (threadIdx.x == 0) {
        float s = 0.0f;
#pragma unroll
        for (int i = 0; i < WPB; ++i) s += blk[i];
        partials[blockIdx.x] = s;
    }
}

__global__ __launch_bounds__(256) void sgns_reduce(
    const float* __restrict__ partials, float* __restrict__ out)
{
    float s = 0.0f;
    for (int i = threadIdx.x; i < NBLOCKS; i += 256) s += partials[i];
#pragma unroll
    for (int off = 32; off > 0; off >>= 1) s += __shfl_xor(s, off, 64);
    __shared__ float lds[4];
    if ((threadIdx.x & 63) == 0) lds[threadIdx.x >> 6] = s;
    __syncthreads();
    if (threadIdx.x == 0) out[0] = lds[0] + lds[1] + lds[2] + lds[3];
}

extern "C" void kernel_launch(void* const* d_in, const int* in_sizes, int n_in,
                              void* d_out, int out_size, void* d_ws, size_t ws_size,
                              hipStream_t stream) {
    const float* ctx     = (const float*)d_in[0];
    const float* tgt     = (const float*)d_in[1];
    const float* emb     = (const float*)d_in[2];
    const int*   neg_idx = (const int*)d_in[3];
    float* out      = (float*)d_out;
    float* partials = (float*)d_ws;  // NBLOCKS floats = 8 KB

    sgns_main<<<NBLOCKS, BLOCK, 0, stream>>>(ctx, tgt, emb, neg_idx, partials);
    sgns_reduce<<<1, 256, 0, stream>>>(partials, out);
}